// Round 7
// baseline (39.320 us; speedup 1.0000x reference)
//
#include <hip/hip_runtime.h>

constexpr int PL = 128;

typedef float f32x2 __attribute__((ext_vector_type(2)));

__device__ __forceinline__ float fast_exp2(float x) {
#if __has_builtin(__builtin_amdgcn_exp2f)
    return __builtin_amdgcn_exp2f(x);
#else
    return __expf(x * 0.69314718055994531f);   // e^(x ln2) = 2^x
#endif
}
// exact IEEE f32 fma per lane; backend selects v_pk_fma_f32 (proven rounds 5/6)
__device__ __forceinline__ f32x2 pk_fma(f32x2 a, f32x2 b, f32x2 c) {
    return __builtin_elementwise_fma(a, b, c);
}
__device__ __forceinline__ f32x2 sp(float v) { f32x2 r; r.x = v; r.y = v; return r; }

__global__ __launch_bounds__(256, 8) void fused_block_kernel(
    const float* __restrict__ x, const float* __restrict__ t, const int* __restrict__ mask,
    const float* __restrict__ Wq, const float* __restrict__ Wk, const float* __restrict__ Wv,
    const float* __restrict__ Wout, const float* __restrict__ W1, const float* __restrict__ b1,
    const float* __restrict__ W2, const float* __restrict__ b2,
    float* __restrict__ out)
{
    // head-independent per-position data, j-pair SoA:
    // CSM[jp*3+0] = {x*c0(2j), x*c0(2j+1), x*s0, x*s0'}
    // CSM[jp*3+1] = {x*c1, x*c1', x*s1, x*s1'}
    // CSM[jp*3+2] = {valid, valid', valid*x, (valid*x)'}
    __shared__ float4 CSM[64 * 3];
    __shared__ f32x2  w1p[32][16];      // [hid-pair][dim] = {W1[2p][d], W1[2p+1][d]}
    __shared__ __align__(8) float cg[64];
    __shared__ __align__(8) float b1s[64];
    __shared__ float  OST[4][PL];       // SoA: per-head attention scalar per row
    __shared__ float  P[2][PL];
    __shared__ float  xpart[2];
    __shared__ __align__(16) float woutS[16];
    __shared__ float  bbS;

    const int tid = threadIdx.x;
    const int b   = blockIdx.x;

    // ---- Phase 1 (waves 0-1): trig staging; (waves 2-3): weight staging ----
    if (tid < PL) {
        const int j  = tid;
        const int jp = j >> 1, p = j & 1;
        const float xv = x[b * PL + j];
        const float tv = t[b * PL + j];
        const int   mv = mask[b * PL + j];
        const float va = mv ? 1.0f : 0.0f;
        const float th1 = 0.031622776601683794f;   // 1000^-0.5
        const float c0 = __cosf(tv),       s0 = __sinf(tv);
        const float c1 = __cosf(tv * th1), s1 = __sinf(tv * th1);
        float* CSMf = reinterpret_cast<float*>(CSM);
        CSMf[jp*12 + 0 + p] = xv * c0;
        CSMf[jp*12 + 2 + p] = xv * s0;
        CSMf[jp*12 + 4 + p] = xv * c1;
        CSMf[jp*12 + 6 + p] = xv * s1;
        CSMf[jp*12 + 8 + p] = va;
        CSMf[jp*12 +10 + p] = va * xv;
        float px = xv;
        #pragma unroll
        for (int off = 32; off >= 1; off >>= 1) px += __shfl_xor(px, off);
        if ((tid & 63) == 0) xpart[tid >> 6] = px;
    } else {
        const int t2 = tid - 128;
        #pragma unroll
        for (int k = 0; k < 8; ++k) {
            const int idx = t2 + k * 128;
            const int hid = idx >> 4, d = idx & 15;
            reinterpret_cast<float*>(w1p)[((hid >> 1) * 16 + d) * 2 + (hid & 1)] = W1[idx];
        }
        if (t2 < 64) {
            b1s[t2] = b1[t2];
            float c = 0.f;
            #pragma unroll
            for (int d = 0; d < 16; ++d) c += W2[d * 64 + t2] * Wout[d];   // W2^T @ wout
            cg[t2] = c;
        }
        if (t2 < 16) woutS[t2] = Wout[t2];
        if (t2 == 0) {
            float bb = 0.f;
            #pragma unroll
            for (int d = 0; d < 16; ++d) bb += b2[d] * Wout[d];
            bbS = bb;
        }
    }
    __syncthreads();

    // ---- Phase 2: attention (relative-position form); wave = head, 2 rows/thread ----
    {
        const int h  = tid >> 6;            // wave-uniform head
        const int rA = tid & 63;
        const int rB = rA + 64;
        const float4 wq4 = reinterpret_cast<const float4*>(Wq)[h];
        const float4 wk4 = reinterpret_cast<const float4*>(Wk)[h];
        const float a0  = wq4.x*wk4.x + wq4.y*wk4.y;
        const float be0 = wq4.x*wk4.y - wq4.y*wk4.x;
        const float a1  = wq4.z*wk4.z + wq4.w*wk4.w;
        const float be1 = wq4.z*wk4.w - wq4.w*wk4.z;
        const float gam = 0.5f * 1.4426950408889634f;   // 1/sqrt(QK) * log2(e)

        const float* CSMf = reinterpret_cast<const float*>(CSM);
        float vr[2];
        f32x2 A[2], Bc[2], Cc[2], Dc[2];
        #pragma unroll
        for (int rr = 0; rr < 2; ++rr) {
            const int r = rr ? rB : rA;
            const int base = (r >> 1) * 12 + (r & 1);
            const float xc0 = CSMf[base + 0], xs0 = CSMf[base + 2];
            const float xc1 = CSMf[base + 4], xs1 = CSMf[base + 6];
            vr[rr] = CSMf[base + 8];
            A[rr]  = sp(gam * (xc0 * a0 + xs0 * be0));
            Bc[rr] = sp(gam * (xs0 * a0 - xc0 * be0));
            Cc[rr] = sp(gam * (xc1 * a1 + xs1 * be1));
            Dc[rr] = sp(gam * (xs1 * a1 - xc1 * be1));
        }
        f32x2 S0 = sp(0.f), X0 = sp(0.f), S1 = sp(0.f), X1 = sp(0.f);

        #pragma unroll 4
        for (int jj = 0; jj < 64; ++jj) {
            const float4 ca = CSM[jj * 3 + 0];   // broadcast b128
            const float4 cb = CSM[jj * 3 + 1];
            const float4 mm = CSM[jj * 3 + 2];
            f32x2 c0p; c0p.x = ca.x; c0p.y = ca.y;
            f32x2 s0p; s0p.x = ca.z; s0p.y = ca.w;
            f32x2 c1p; c1p.x = cb.x; c1p.y = cb.y;
            f32x2 s1p; s1p.x = cb.z; s1p.y = cb.w;
            f32x2 vv;  vv.x  = mm.x; vv.y  = mm.y;
            f32x2 vx;  vx.x  = mm.z; vx.y  = mm.w;
            f32x2 L0 = A[0] * c0p;
            L0 = pk_fma(Bc[0], s0p, L0);
            L0 = pk_fma(Cc[0], c1p, L0);
            L0 = pk_fma(Dc[0], s1p, L0);
            f32x2 L1 = A[1] * c0p;
            L1 = pk_fma(Bc[1], s0p, L1);
            L1 = pk_fma(Cc[1], c1p, L1);
            L1 = pk_fma(Dc[1], s1p, L1);
            f32x2 E0, E1;
            E0.x = fast_exp2(L0.x); E0.y = fast_exp2(L0.y);
            E1.x = fast_exp2(L1.x); E1.y = fast_exp2(L1.y);
            S0 = pk_fma(E0, vv, S0);  X0 = pk_fma(E0, vx, X0);
            S1 = pk_fma(E1, vv, S1);  X1 = pk_fma(E1, vx, X1);
        }
        const float sumx = xpart[0] + xpart[1];
        {
            const float s = S0.x + S0.y, wx = X0.x + X0.y;
            const bool  m = vr[0] != 0.f;
            OST[h][rA] = (m ? wx : sumx) / (m ? s : 128.f);   // masked row: uniform 1/128
        }
        {
            const float s = S1.x + S1.y, wx = X1.x + X1.y;
            const bool  m = vr[1] != 0.f;
            OST[h][rB] = (m ? wx : sumx) / (m ? s : 128.f);
        }
    }
    __syncthreads();

    // ---- Phase 3: o = wv (x) o_scal; out = o.wout + bb + sum cg*relu(o.W1+b1) ----
    {
        const int qi   = tid & (PL - 1);
        const int half = tid >> 7;
        const float os0 = OST[0][qi], os1 = OST[1][qi], os2 = OST[2][qi], os3 = OST[3][qi];
        const float4 wv0 = reinterpret_cast<const float4*>(Wv)[0];
        const float4 wv1 = reinterpret_cast<const float4*>(Wv)[1];
        const float4 wv2 = reinterpret_cast<const float4*>(Wv)[2];
        const float4 wv3 = reinterpret_cast<const float4*>(Wv)[3];
        float o[16];
        o[ 0] = wv0.x*os0; o[ 1] = wv0.y*os0; o[ 2] = wv0.z*os0; o[ 3] = wv0.w*os0;
        o[ 4] = wv1.x*os1; o[ 5] = wv1.y*os1; o[ 6] = wv1.z*os1; o[ 7] = wv1.w*os1;
        o[ 8] = wv2.x*os2; o[ 9] = wv2.y*os2; o[10] = wv2.z*os2; o[11] = wv2.w*os2;
        o[12] = wv3.x*os3; o[13] = wv3.y*os3; o[14] = wv3.z*os3; o[15] = wv3.w*os3;

        const f32x2* b1pair = reinterpret_cast<const f32x2*>(b1s);
        const f32x2* cgpair = reinterpret_cast<const f32x2*>(cg);
        f32x2 R2 = sp(0.f);
        const int p0 = half * 16;
        #pragma unroll 4
        for (int pp = 0; pp < 16; ++pp) {
            const int p = p0 + pp;
            f32x2 HS = b1pair[p];
            #pragma unroll
            for (int d = 0; d < 16; ++d) HS = pk_fma(w1p[p][d], sp(o[d]), HS);
            HS.x = fmaxf(HS.x, 0.f);
            HS.y = fmaxf(HS.y, 0.f);
            R2 = pk_fma(cgpair[p], HS, R2);
        }
        float r = R2.x + R2.y;
        if (half == 0) {
            float r2 = bbS;
            #pragma unroll
            for (int d = 0; d < 16; ++d) r2 += o[d] * woutS[d];
            r += r2;
        }
        P[half][qi] = r;
    }
    __syncthreads();
    if (tid < PL) out[b * PL + tid] = P[0][tid] + P[1][tid];
}

extern "C" void kernel_launch(void* const* d_in, const int* in_sizes, int n_in,
                              void* d_out, int out_size, void* d_ws, size_t ws_size,
                              hipStream_t stream) {
    const float* x    = (const float*)d_in[0];
    const float* t    = (const float*)d_in[1];
    const int*   mask = (const int*)d_in[2];
    const float* Wq   = (const float*)d_in[3];
    const float* Wk   = (const float*)d_in[4];
    const float* Wv   = (const float*)d_in[5];
    const float* Wout = (const float*)d_in[6];
    const float* W1   = (const float*)d_in[7];
    const float* b1   = (const float*)d_in[8];
    const float* W2   = (const float*)d_in[9];
    const float* b2   = (const float*)d_in[10];
    float* outp = (float*)d_out;
    const int B = in_sizes[0] / PL;  // 2048 sequences
    fused_block_kernel<<<B, 256, 0, stream>>>(x, t, mask, Wq, Wk, Wv, Wout, W1, b1, W2, b2, outp);
}

// Round 8
// 35.666 us; speedup vs baseline: 1.1024x; 1.1024x over previous
//
#include <hip/hip_runtime.h>

constexpr int PL = 128;

typedef float f32x2 __attribute__((ext_vector_type(2)));

__device__ __forceinline__ float fast_exp2(float x) {
#if __has_builtin(__builtin_amdgcn_exp2f)
    return __builtin_amdgcn_exp2f(x);
#else
    return __expf(x * 0.69314718055994531f);   // e^(x ln2) = 2^x
#endif
}
// exact IEEE f32 fma per lane; backend selects v_pk_fma_f32 (proven rounds 5/6)
__device__ __forceinline__ f32x2 pk_fma(f32x2 a, f32x2 b, f32x2 c) {
    return __builtin_elementwise_fma(a, b, c);
}
__device__ __forceinline__ f32x2 sp(float v) { f32x2 r; r.x = v; r.y = v; return r; }

__global__ __launch_bounds__(256, 4) void fused_block_kernel(
    const float* __restrict__ x, const float* __restrict__ t, const int* __restrict__ mask,
    const float* __restrict__ Wq, const float* __restrict__ Wk, const float* __restrict__ Wv,
    const float* __restrict__ Wout, const float* __restrict__ W1, const float* __restrict__ b1,
    const float* __restrict__ W2, const float* __restrict__ b2,
    float* __restrict__ out)
{
    // head-independent per-position data, j-pair SoA:
    // CSM[jp*3+0] = {x*c0(2j), x*c0(2j+1), x*s0, x*s0'}
    // CSM[jp*3+1] = {x*c1, x*c1', x*s1, x*s1'}
    // CSM[jp*3+2] = {valid, valid', valid*x, (valid*x)'}
    __shared__ float4 CSM[64 * 3];
    __shared__ f32x2  w1p[32][16];      // [hid-pair][dim] = {W1[2p][d], W1[2p+1][d]}
    __shared__ __align__(8) float cg[64];
    __shared__ __align__(8) float b1s[64];
    __shared__ float  OST[4][PL];       // SoA: per-head attention scalar per row
    __shared__ float  P[2][PL];
    __shared__ float  xpart[2];
    __shared__ __align__(16) float woutS[16];
    __shared__ float  bbS;

    const int tid = threadIdx.x;
    const int b   = blockIdx.x;

    // ---- Phase 1 (waves 0-1): trig staging; (waves 2-3): weight staging ----
    if (tid < PL) {
        const int j  = tid;
        const int jp = j >> 1, p = j & 1;
        const float xv = x[b * PL + j];
        const float tv = t[b * PL + j];
        const int   mv = mask[b * PL + j];
        const float va = mv ? 1.0f : 0.0f;
        const float th1 = 0.031622776601683794f;   // 1000^-0.5
        const float c0 = __cosf(tv),       s0 = __sinf(tv);
        const float c1 = __cosf(tv * th1), s1 = __sinf(tv * th1);
        float* CSMf = reinterpret_cast<float*>(CSM);
        CSMf[jp*12 + 0 + p] = xv * c0;
        CSMf[jp*12 + 2 + p] = xv * s0;
        CSMf[jp*12 + 4 + p] = xv * c1;
        CSMf[jp*12 + 6 + p] = xv * s1;
        CSMf[jp*12 + 8 + p] = va;
        CSMf[jp*12 +10 + p] = va * xv;
        float px = xv;
        #pragma unroll
        for (int off = 32; off >= 1; off >>= 1) px += __shfl_xor(px, off);
        if ((tid & 63) == 0) xpart[tid >> 6] = px;
    } else {
        const int t2 = tid - 128;
        #pragma unroll
        for (int k = 0; k < 8; ++k) {
            const int idx = t2 + k * 128;
            const int hid = idx >> 4, d = idx & 15;
            reinterpret_cast<float*>(w1p)[((hid >> 1) * 16 + d) * 2 + (hid & 1)] = W1[idx];
        }
        if (t2 < 64) {
            b1s[t2] = b1[t2];
            float c = 0.f;
            #pragma unroll
            for (int d = 0; d < 16; ++d) c += W2[d * 64 + t2] * Wout[d];   // W2^T @ wout
            cg[t2] = c;
        }
        if (t2 < 16) woutS[t2] = Wout[t2];
        if (t2 == 0) {
            float bb = 0.f;
            #pragma unroll
            for (int d = 0; d < 16; ++d) bb += b2[d] * Wout[d];
            bbS = bb;
        }
    }
    __syncthreads();

    // ---- Phase 2: attention (relative-position form); wave = head, 2 rows/thread ----
    {
        const int h  = tid >> 6;            // wave-uniform head
        const int rA = tid & 63;
        const int rB = rA + 64;
        const float4 wq4 = reinterpret_cast<const float4*>(Wq)[h];
        const float4 wk4 = reinterpret_cast<const float4*>(Wk)[h];
        const float a0  = wq4.x*wk4.x + wq4.y*wk4.y;
        const float be0 = wq4.x*wk4.y - wq4.y*wk4.x;
        const float a1  = wq4.z*wk4.z + wq4.w*wk4.w;
        const float be1 = wq4.z*wk4.w - wq4.w*wk4.z;
        const float gam = 0.5f * 1.4426950408889634f;   // 1/sqrt(QK) * log2(e)

        const float* CSMf = reinterpret_cast<const float*>(CSM);
        float vr[2];
        f32x2 A[2], Bc[2], Cc[2], Dc[2];
        #pragma unroll
        for (int rr = 0; rr < 2; ++rr) {
            const int r = rr ? rB : rA;
            const int base = (r >> 1) * 12 + (r & 1);
            const float xc0 = CSMf[base + 0], xs0 = CSMf[base + 2];
            const float xc1 = CSMf[base + 4], xs1 = CSMf[base + 6];
            vr[rr] = CSMf[base + 8];
            A[rr]  = sp(gam * (xc0 * a0 + xs0 * be0));
            Bc[rr] = sp(gam * (xs0 * a0 - xc0 * be0));
            Cc[rr] = sp(gam * (xc1 * a1 + xs1 * be1));
            Dc[rr] = sp(gam * (xs1 * a1 - xc1 * be1));
        }
        f32x2 S0 = sp(0.f), X0 = sp(0.f), S1 = sp(0.f), X1 = sp(0.f);

        #pragma unroll 4
        for (int jj = 0; jj < 64; ++jj) {
            const float4 ca = CSM[jj * 3 + 0];   // broadcast b128
            const float4 cb = CSM[jj * 3 + 1];
            const float4 mm = CSM[jj * 3 + 2];
            f32x2 c0p; c0p.x = ca.x; c0p.y = ca.y;
            f32x2 s0p; s0p.x = ca.z; s0p.y = ca.w;
            f32x2 c1p; c1p.x = cb.x; c1p.y = cb.y;
            f32x2 s1p; s1p.x = cb.z; s1p.y = cb.w;
            f32x2 vv;  vv.x  = mm.x; vv.y  = mm.y;
            f32x2 vx;  vx.x  = mm.z; vx.y  = mm.w;
            f32x2 L0 = A[0] * c0p;
            L0 = pk_fma(Bc[0], s0p, L0);
            L0 = pk_fma(Cc[0], c1p, L0);
            L0 = pk_fma(Dc[0], s1p, L0);
            f32x2 L1 = A[1] * c0p;
            L1 = pk_fma(Bc[1], s0p, L1);
            L1 = pk_fma(Cc[1], c1p, L1);
            L1 = pk_fma(Dc[1], s1p, L1);
            f32x2 E0, E1;
            E0.x = fast_exp2(L0.x); E0.y = fast_exp2(L0.y);
            E1.x = fast_exp2(L1.x); E1.y = fast_exp2(L1.y);
            S0 = pk_fma(E0, vv, S0);  X0 = pk_fma(E0, vx, X0);
            S1 = pk_fma(E1, vv, S1);  X1 = pk_fma(E1, vx, X1);
        }
        const float sumx = xpart[0] + xpart[1];
        {
            const float s = S0.x + S0.y, wx = X0.x + X0.y;
            const bool  m = vr[0] != 0.f;
            OST[h][rA] = (m ? wx : sumx) / (m ? s : 128.f);   // masked row: uniform 1/128
        }
        {
            const float s = S1.x + S1.y, wx = X1.x + X1.y;
            const bool  m = vr[1] != 0.f;
            OST[h][rB] = (m ? wx : sumx) / (m ? s : 128.f);
        }
    }
    __syncthreads();

    // ---- Phase 3: o = wv (x) o_scal; out = o.wout + bb + sum cg*relu(o.W1+b1) ----
    {
        const int qi   = tid & (PL - 1);
        const int half = tid >> 7;
        const float os0 = OST[0][qi], os1 = OST[1][qi], os2 = OST[2][qi], os3 = OST[3][qi];
        const float4 wv0 = reinterpret_cast<const float4*>(Wv)[0];
        const float4 wv1 = reinterpret_cast<const float4*>(Wv)[1];
        const float4 wv2 = reinterpret_cast<const float4*>(Wv)[2];
        const float4 wv3 = reinterpret_cast<const float4*>(Wv)[3];
        float o[16];
        o[ 0] = wv0.x*os0; o[ 1] = wv0.y*os0; o[ 2] = wv0.z*os0; o[ 3] = wv0.w*os0;
        o[ 4] = wv1.x*os1; o[ 5] = wv1.y*os1; o[ 6] = wv1.z*os1; o[ 7] = wv1.w*os1;
        o[ 8] = wv2.x*os2; o[ 9] = wv2.y*os2; o[10] = wv2.z*os2; o[11] = wv2.w*os2;
        o[12] = wv3.x*os3; o[13] = wv3.y*os3; o[14] = wv3.z*os3; o[15] = wv3.w*os3;

        const f32x2* b1pair = reinterpret_cast<const f32x2*>(b1s);
        const f32x2* cgpair = reinterpret_cast<const f32x2*>(cg);
        f32x2 R2 = sp(0.f);
        const int p0 = half * 16;
        #pragma unroll 4
        for (int pp = 0; pp < 16; ++pp) {
            const int p = p0 + pp;
            f32x2 HS = b1pair[p];
            #pragma unroll
            for (int d = 0; d < 16; ++d) HS = pk_fma(w1p[p][d], sp(o[d]), HS);
            HS.x = fmaxf(HS.x, 0.f);
            HS.y = fmaxf(HS.y, 0.f);
            R2 = pk_fma(cgpair[p], HS, R2);
        }
        float r = R2.x + R2.y;
        if (half == 0) {
            float r2 = bbS;
            #pragma unroll
            for (int d = 0; d < 16; ++d) r2 += o[d] * woutS[d];
            r += r2;
        }
        P[half][qi] = r;
    }
    __syncthreads();
    if (tid < PL) out[b * PL + tid] = P[0][tid] + P[1][tid];
}

extern "C" void kernel_launch(void* const* d_in, const int* in_sizes, int n_in,
                              void* d_out, int out_size, void* d_ws, size_t ws_size,
                              hipStream_t stream) {
    const float* x    = (const float*)d_in[0];
    const float* t    = (const float*)d_in[1];
    const int*   mask = (const int*)d_in[2];
    const float* Wq   = (const float*)d_in[3];
    const float* Wk   = (const float*)d_in[4];
    const float* Wv   = (const float*)d_in[5];
    const float* Wout = (const float*)d_in[6];
    const float* W1   = (const float*)d_in[7];
    const float* b1   = (const float*)d_in[8];
    const float* W2   = (const float*)d_in[9];
    const float* b2   = (const float*)d_in[10];
    float* outp = (float*)d_out;
    const int B = in_sizes[0] / PL;  // 2048 sequences
    fused_block_kernel<<<B, 256, 0, stream>>>(x, t, mask, Wq, Wk, Wv, Wout, W1, b1, W2, b2, outp);
}

// Round 10
// 34.697 us; speedup vs baseline: 1.1332x; 1.0279x over previous
//
#include <hip/hip_runtime.h>

constexpr int PL = 128;

typedef float f32x2 __attribute__((ext_vector_type(2)));

__device__ __forceinline__ float fast_exp2(float x) {
#if __has_builtin(__builtin_amdgcn_exp2f)
    return __builtin_amdgcn_exp2f(x);
#else
    return __expf(x * 0.69314718055994531f);   // e^(x ln2) = 2^x
#endif
}
// exact IEEE f32 fma per lane; backend selects v_pk_fma_f32 (proven rounds 5-8)
__device__ __forceinline__ f32x2 pk_fma(f32x2 a, f32x2 b, f32x2 c) {
    return __builtin_elementwise_fma(a, b, c);
}
__device__ __forceinline__ f32x2 sp(float v) { f32x2 r; r.x = v; r.y = v; return r; }

__global__ __launch_bounds__(256, 4) void fused_block_kernel(
    const float* __restrict__ x, const float* __restrict__ t, const int* __restrict__ mask,
    const float* __restrict__ Wq, const float* __restrict__ Wk, const float* __restrict__ Wv,
    const float* __restrict__ Wout, const float* __restrict__ W1, const float* __restrict__ b1,
    const float* __restrict__ W2, const float* __restrict__ b2,
    float* __restrict__ out)
{
    // Two sequences per block. Head-independent per-position data, j-pair SoA:
    // CSM[s][jp*3+0] = {x*c0(2j), x*c0(2j+1), x*s0, x*s0'}
    // CSM[s][jp*3+1] = {x*c1, x*c1', x*s1, x*s1'}
    // CSM[s][jp*3+2] = {valid, valid', valid*x, (valid*x)'}
    __shared__ float4 CSM[2][64 * 3];
    __shared__ f32x2  w1p[32][16];      // [hid-pair][dim] = {W1[2p][d], W1[2p+1][d]}
    __shared__ __align__(8) float cg[64];
    __shared__ __align__(8) float b1s[64];
    __shared__ float  OST[2][4][PL];    // per-seq per-head attention scalar per row
    __shared__ float  xpart[2][2];
    __shared__ __align__(16) float woutS[16];
    __shared__ float  bbS;

    const int tid = threadIdx.x;
    const int blk = blockIdx.x;         // sequences 2*blk, 2*blk+1

    // ---- Phase 1: trig staging (all threads; thread -> (seq, position)) ----
    {
        const int seq = tid >> 7;
        const int j   = tid & 127;
        const int gb  = blk * 2 + seq;
        const int jp  = j >> 1, p = j & 1;
        const float xv = x[gb * PL + j];
        const float tv = t[gb * PL + j];
        const int   mv = mask[gb * PL + j];
        const float va = mv ? 1.0f : 0.0f;
        const float th1 = 0.031622776601683794f;   // 1000^-0.5
        const float c0 = __cosf(tv),       s0 = __sinf(tv);
        const float c1 = __cosf(tv * th1), s1 = __sinf(tv * th1);
        float* CSMf = reinterpret_cast<float*>(CSM[seq]);
        CSMf[jp*12 + 0 + p] = xv * c0;
        CSMf[jp*12 + 2 + p] = xv * s0;
        CSMf[jp*12 + 4 + p] = xv * c1;
        CSMf[jp*12 + 6 + p] = xv * s1;
        CSMf[jp*12 + 8 + p] = va;
        CSMf[jp*12 +10 + p] = va * xv;
        float px = xv;
        #pragma unroll
        for (int off = 32; off >= 1; off >>= 1) px += __shfl_xor(px, off);
        if ((tid & 63) == 0) xpart[seq][(tid >> 6) & 1] = px;
    }
    // ---- weight staging (all threads; small) ----
    #pragma unroll
    for (int k = 0; k < 4; ++k) {
        const int idx = tid + k * 256;
        const int hid = idx >> 4, d = idx & 15;
        reinterpret_cast<float*>(w1p)[((hid >> 1) * 16 + d) * 2 + (hid & 1)] = W1[idx];
    }
    if (tid < 64) {
        b1s[tid] = b1[tid];
        float c = 0.f;
        #pragma unroll
        for (int d = 0; d < 16; ++d) c += W2[d * 64 + tid] * Wout[d];   // W2^T @ wout
        cg[tid] = c;
    }
    if (tid < 16) woutS[tid] = Wout[tid];
    if (tid == 0) {
        float bb = 0.f;
        #pragma unroll
        for (int d = 0; d < 16; ++d) bb += b2[d] * Wout[d];
        bbS = bb;
    }
    __syncthreads();

    // ---- Phase 2: attention (relative-position form); 4 same-seq rows per lane ----
    {
        const int wave = tid >> 6;
        const int seq  = wave >> 1;
        const int lane = tid & 63;
        const int h    = (wave & 1) * 2 + (lane >> 5);   // 2 heads per wave
        const int r0   = lane & 31;                      // rows r0 + 32*rr
        const float4 wq4 = reinterpret_cast<const float4*>(Wq)[h];
        const float4 wk4 = reinterpret_cast<const float4*>(Wk)[h];
        const float a0  = wq4.x*wk4.x + wq4.y*wk4.y;
        const float be0 = wq4.x*wk4.y - wq4.y*wk4.x;
        const float a1  = wq4.z*wk4.z + wq4.w*wk4.w;
        const float be1 = wq4.z*wk4.w - wq4.w*wk4.z;
        const float gam = 0.5f * 1.4426950408889634f;    // 1/sqrt(QK) * log2(e)

        const float* CSMf = reinterpret_cast<const float*>(CSM[seq]);
        float vr[4];
        f32x2 A[4], Bc[4], Cc[4], Dc[4], S[4], X[4];
        #pragma unroll
        for (int rr = 0; rr < 4; ++rr) {
            const int r = r0 + rr * 32;
            const int base = (r >> 1) * 12 + (r & 1);
            const float xc0 = CSMf[base + 0], xs0 = CSMf[base + 2];
            const float xc1 = CSMf[base + 4], xs1 = CSMf[base + 6];
            vr[rr] = CSMf[base + 8];
            A[rr]  = sp(gam * (xc0 * a0 + xs0 * be0));
            Bc[rr] = sp(gam * (xs0 * a0 - xc0 * be0));
            Cc[rr] = sp(gam * (xc1 * a1 + xs1 * be1));
            Dc[rr] = sp(gam * (xs1 * a1 - xc1 * be1));
            S[rr] = sp(0.f);
            X[rr] = sp(0.f);
        }

        #pragma unroll 2
        for (int jj = 0; jj < 64; ++jj) {
            const float4 ca = CSM[seq][jj * 3 + 0];   // wave-uniform broadcast b128
            const float4 cb = CSM[seq][jj * 3 + 1];
            const float4 mm = CSM[seq][jj * 3 + 2];
            f32x2 c0p; c0p.x = ca.x; c0p.y = ca.y;
            f32x2 s0p; s0p.x = ca.z; s0p.y = ca.w;
            f32x2 c1p; c1p.x = cb.x; c1p.y = cb.y;
            f32x2 s1p; s1p.x = cb.z; s1p.y = cb.w;
            f32x2 vv;  vv.x  = mm.x; vv.y  = mm.y;
            f32x2 vx;  vx.x  = mm.z; vx.y  = mm.w;
            #pragma unroll
            for (int rr = 0; rr < 4; ++rr) {
                f32x2 L = A[rr] * c0p;
                L = pk_fma(Bc[rr], s0p, L);
                L = pk_fma(Cc[rr], c1p, L);
                L = pk_fma(Dc[rr], s1p, L);
                f32x2 E;
                E.x = fast_exp2(L.x);
                E.y = fast_exp2(L.y);
                S[rr] = pk_fma(E, vv, S[rr]);
                X[rr] = pk_fma(E, vx, X[rr]);
            }
        }
        const float sumx = xpart[seq][0] + xpart[seq][1];
        #pragma unroll
        for (int rr = 0; rr < 4; ++rr) {
            const int r = r0 + rr * 32;
            const float s  = S[rr].x + S[rr].y;
            const float wx = X[rr].x + X[rr].y;
            const bool  m  = vr[rr] != 0.f;
            // masked query row: uniform softmax over ALL j -> o_scal = sumx/128
            OST[seq][h][r] = (m ? wx : sumx) / (m ? s : 128.f);
        }
    }
    __syncthreads();

    // ---- Phase 3: o = wv (x) o_scal; out = o.wout + bb + sum cg*relu(o.W1+b1) ----
    {
        const int seq = tid >> 7;
        const int qi  = tid & 127;
        const float os0 = OST[seq][0][qi], os1 = OST[seq][1][qi];
        const float os2 = OST[seq][2][qi], os3 = OST[seq][3][qi];
        const float4 wv0 = reinterpret_cast<const float4*>(Wv)[0];
        const float4 wv1 = reinterpret_cast<const float4*>(Wv)[1];
        const float4 wv2 = reinterpret_cast<const float4*>(Wv)[2];
        const float4 wv3 = reinterpret_cast<const float4*>(Wv)[3];
        float o[16];
        o[ 0] = wv0.x*os0; o[ 1] = wv0.y*os0; o[ 2] = wv0.z*os0; o[ 3] = wv0.w*os0;
        o[ 4] = wv1.x*os1; o[ 5] = wv1.y*os1; o[ 6] = wv1.z*os1; o[ 7] = wv1.w*os1;
        o[ 8] = wv2.x*os2; o[ 9] = wv2.y*os2; o[10] = wv2.z*os2; o[11] = wv2.w*os2;
        o[12] = wv3.x*os3; o[13] = wv3.y*os3; o[14] = wv3.z*os3; o[15] = wv3.w*os3;

        const f32x2* b1pair = reinterpret_cast<const f32x2*>(b1s);
        const f32x2* cgpair = reinterpret_cast<const f32x2*>(cg);
        f32x2 R2 = sp(0.f);
        #pragma unroll 4
        for (int p = 0; p < 32; ++p) {
            f32x2 HS = b1pair[p];
            #pragma unroll
            for (int d = 0; d < 16; ++d) HS = pk_fma(w1p[p][d], sp(o[d]), HS);
            HS.x = fmaxf(HS.x, 0.f);
            HS.y = fmaxf(HS.y, 0.f);
            R2 = pk_fma(cgpair[p], HS, R2);
        }
        float r = R2.x + R2.y + bbS;
        #pragma unroll
        for (int d = 0; d < 16; ++d) r += o[d] * woutS[d];
        out[(blk * 2 + seq) * PL + qi] = r;
    }
}

extern "C" void kernel_launch(void* const* d_in, const int* in_sizes, int n_in,
                              void* d_out, int out_size, void* d_ws, size_t ws_size,
                              hipStream_t stream) {
    const float* x    = (const float*)d_in[0];
    const float* t    = (const float*)d_in[1];
    const int*   mask = (const int*)d_in[2];
    const float* Wq   = (const float*)d_in[3];
    const float* Wk   = (const float*)d_in[4];
    const float* Wv   = (const float*)d_in[5];
    const float* Wout = (const float*)d_in[6];
    const float* W1   = (const float*)d_in[7];
    const float* b1   = (const float*)d_in[8];
    const float* W2   = (const float*)d_in[9];
    const float* b2   = (const float*)d_in[10];
    float* outp = (float*)d_out;
    const int B  = in_sizes[0] / PL;    // 2048 sequences
    const int B2 = B / 2;               // 2 sequences per block
    fused_block_kernel<<<B2, 256, 0, stream>>>(x, t, mask, Wq, Wk, Wv, Wout, W1, b1, W2, b2, outp);
}